// Round 1
// baseline (181.619 us; speedup 1.0000x reference)
//
#include <hip/hip_runtime.h>
#include <hip/hip_bf16.h>
#include <math.h>

// MyAttentionHead: B=4, S=2048, d_model=1024, d_head=64. fp32 in/out storage.
// Associativity rewrite: out = ((P~ @ xv) * 1/l) @ O^T  (instead of P~ @ (xv@O^T)).
// K0 wprep, K1a qkv_part MFMA (K-split 4), K1b qkv_reduce (+xv transpose),
// K3 softmax MFMA (unchanged: paired q-tiles, 4-way k-split, unnormalized P~),
// K4 pv: Axv_part = P~ @ xv  (paired m-tiles, 8-way k-split, BK=64 dbuf swizzled LDS),
// K5 out: reduce partials, scale 1/l, hi/lo bf16 GEMM vs O -> fp32 out.
#define BATCH 4
#define SEQ   2048
#define DM    1024
#define DH    64
#define NROWS (BATCH*SEQ)   // 8192
#define PVSPLIT 8

typedef __hip_bfloat16 bf16;
typedef __attribute__((ext_vector_type(8))) short short8;
typedef __attribute__((ext_vector_type(8))) unsigned short ushortx8;
typedef __attribute__((ext_vector_type(4))) float floatx4;

__device__ __forceinline__ ushort f2bf(float f) {
    union { bf16 h; ushort u; } cv;
    cv.h = __float2bfloat16(f);
    return cv.u;
}
__device__ __forceinline__ float bf2f(ushort u) {
    union { unsigned int i; float f; } v; v.i = ((unsigned int)u) << 16; return v.f;
}

// async 16B global->LDS: lds dest = wave-uniform base + lane*16
__device__ __forceinline__ void load_lds16(const ushort* g, ushort* l) {
    __builtin_amdgcn_global_load_lds(
        (const __attribute__((address_space(1))) unsigned int*)g,
        (__attribute__((address_space(3))) unsigned int*)l, 16, 0, 0);
}

// ---------------- K0: weight prep ----------------
__global__ __launch_bounds__(256) void wprep_kernel(
    const float* __restrict__ Q, const float* __restrict__ K,
    const float* __restrict__ V, ushort* __restrict__ WhT, ushort* __restrict__ WlT)
{
    int n = blockIdx.x;                       // 0..191
    const float* W = (n < 64) ? Q : (n < 128) ? K : V;
    int c = n & 63;
    for (int k = threadIdx.x; k < DM; k += 256) {
        float w = W[k * DH + c];
        ushort hi = f2bf(w);
        WhT[n * DM + k] = hi;
        WlT[n * DM + k] = f2bf(w - bf2f(hi));
    }
}

// ---------------- K1a: qkv partial MFMA (K-split 4) ----------------
__global__ __launch_bounds__(256) void qkv_part_kernel(
    const float* __restrict__ x, const ushort* __restrict__ WhT,
    const ushort* __restrict__ WlT, float* __restrict__ Cpart)
{
    __shared__ __align__(16) ushort Xs[2][32][34];
    __shared__ __align__(16) ushort Ws[2][192][34];
    int s0 = blockIdx.x * 32;
    int kb = blockIdx.y * 256;
    int t = threadIdx.x;
    int wave = t >> 6, lane = t & 63, m_ = lane & 15, qd = lane >> 4;
    const floatx4 z4 = {0.f, 0.f, 0.f, 0.f};
    floatx4 accq[2] = {z4, z4}, acck[2] = {z4, z4}, accv[2] = {z4, z4};
    int xr = t >> 3, xc = (t & 7) * 4;
    for (int k0 = 0; k0 < 256; k0 += 32) {
        float4 v = *(const float4*)&x[(size_t)(s0 + xr) * DM + kb + k0 + xc];
        ushort h0 = f2bf(v.x), h1 = f2bf(v.y), h2 = f2bf(v.z), h3 = f2bf(v.w);
        *(ushort4*)&Xs[0][xr][xc] = make_ushort4(h0, h1, h2, h3);
        *(ushort4*)&Xs[1][xr][xc] = make_ushort4(
            f2bf(v.x - bf2f(h0)), f2bf(v.y - bf2f(h1)),
            f2bf(v.z - bf2f(h2)), f2bf(v.w - bf2f(h3)));
        #pragma unroll
        for (int j = 0; j < 3; ++j) {
            int idx = t + j * 256, n = idx >> 2, kc = (idx & 3) * 8;
            *(uint4*)&Ws[0][n][kc] = *(const uint4*)&WhT[n * DM + kb + k0 + kc];
            *(uint4*)&Ws[1][n][kc] = *(const uint4*)&WlT[n * DM + kb + k0 + kc];
        }
        __syncthreads();
        short8 ah[2], al[2];
        #pragma unroll
        for (int mi = 0; mi < 2; ++mi) {
            ah[mi] = *(const short8*)&Xs[0][mi * 16 + m_][qd * 8];
            al[mi] = *(const short8*)&Xs[1][mi * 16 + m_][qd * 8];
        }
        int nq = wave * 16 + m_, nk = 64 + wave * 16 + m_, nv = 128 + wave * 16 + m_;
        short8 bqh = *(const short8*)&Ws[0][nq][qd * 8];
        short8 bql = *(const short8*)&Ws[1][nq][qd * 8];
        short8 bkh = *(const short8*)&Ws[0][nk][qd * 8];
        short8 bkl = *(const short8*)&Ws[1][nk][qd * 8];
        short8 bvh = *(const short8*)&Ws[0][nv][qd * 8];
        #pragma unroll
        for (int mi = 0; mi < 2; ++mi) {
            accq[mi] = __builtin_amdgcn_mfma_f32_16x16x32_bf16(ah[mi], bqh, accq[mi], 0, 0, 0);
            accq[mi] = __builtin_amdgcn_mfma_f32_16x16x32_bf16(al[mi], bqh, accq[mi], 0, 0, 0);
            accq[mi] = __builtin_amdgcn_mfma_f32_16x16x32_bf16(ah[mi], bql, accq[mi], 0, 0, 0);
            acck[mi] = __builtin_amdgcn_mfma_f32_16x16x32_bf16(ah[mi], bkh, acck[mi], 0, 0, 0);
            acck[mi] = __builtin_amdgcn_mfma_f32_16x16x32_bf16(al[mi], bkh, acck[mi], 0, 0, 0);
            acck[mi] = __builtin_amdgcn_mfma_f32_16x16x32_bf16(ah[mi], bkl, acck[mi], 0, 0, 0);
            accv[mi] = __builtin_amdgcn_mfma_f32_16x16x32_bf16(ah[mi], bvh, accv[mi], 0, 0, 0);
        }
        __syncthreads();
    }
    float* Cp = Cpart + (size_t)blockIdx.y * (NROWS * 192);
    #pragma unroll
    for (int mi = 0; mi < 2; ++mi) {
        #pragma unroll
        for (int r = 0; r < 4; ++r) {
            int row = s0 + mi * 16 + qd * 4 + r;
            float* base = Cp + (size_t)row * 192;
            base[wave * 16 + m_]       = accq[mi][r];
            base[64 + wave * 16 + m_]  = acck[mi][r];
            base[128 + wave * 16 + m_] = accv[mi][r];
        }
    }
}

// ---------------- K1b: reduce partials, split hi/lo, transpose xv ----------------
// 32 rows per block. Writes qh/ql/kh/kl row-major; xv transposed to
// xvhT[b*64+h][2048] via LDS so global writes are 64B-granular.
__global__ __launch_bounds__(256) void qkv_reduce_kernel(
    const float* __restrict__ Cpart,
    ushort* __restrict__ qh, ushort* __restrict__ ql,
    ushort* __restrict__ kh, ushort* __restrict__ kl, ushort* __restrict__ xvhT)
{
    __shared__ ushort xvs[32][72];
    const size_t SL = (size_t)NROWS * 192;
    int row0 = blockIdx.x * 32;
    int t = threadIdx.x;
    #pragma unroll
    for (int i = 0; i < 24; ++i) {
        int e = i * 256 + t;
        int r = e / 192, c = e - r * 192;
        size_t row = row0 + r;
        size_t off = row * 192 + c;
        float s = Cpart[off] + Cpart[SL + off] + Cpart[2 * SL + off] + Cpart[3 * SL + off];
        ushort hi = f2bf(s);
        if (c < 64) {
            qh[row * 64 + c] = hi; ql[row * 64 + c] = f2bf(s - bf2f(hi));
        } else if (c < 128) {
            kh[row * 64 + c - 64] = hi; kl[row * 64 + c - 64] = f2bf(s - bf2f(hi));
        } else {
            xvs[r][c - 128] = hi;
        }
    }
    __syncthreads();
    int h = t >> 2, seg = t & 3;          // 64 h-rows x 4 segments of 8 s
    ushortx8 v;
    #pragma unroll
    for (int k = 0; k < 8; ++k) v[k] = xvs[seg * 8 + k][h];
    int b = row0 >> 11, sl = row0 & 2047;
    *(ushortx8*)&xvhT[(((size_t)(b * 64 + h)) << 11) + sl + seg * 8] = v;
}

// ---------------- K3: softmax MFMA, paired q-tiles + 4-way k-split ----------------
__global__ __launch_bounds__(256) void softmax_kernel(
    const ushort* __restrict__ qh, const ushort* __restrict__ ql,
    const ushort* __restrict__ kh, const ushort* __restrict__ kl,
    ushort* __restrict__ P, float* __restrict__ lpart)
{
    __shared__ __align__(16) ushort Qs[2][2][32][72];  // [tile][hi/lo][row][col]
    __shared__ float lred[4][2][32];
    int pp = blockIdx.x & 31, b = blockIdx.x >> 5, s = blockIdx.y;
    int jA = pp, jB = 63 - pp;
    int srowA = jA << 5, srowB = jB << 5;
    int s0gA = (b << 11) + srowA, s0gB = (b << 11) + srowB;
    int t = threadIdx.x, wave = t >> 6, lane = t & 63, m_ = lane & 15, qd = lane >> 4;
    #pragma unroll
    for (int i = 0; i < 4; ++i) {
        int idx = i * 256 + t;
        int tile = idx >> 9, hl = (idx >> 8) & 1, r = (idx >> 3) & 31, c = (idx & 7) * 8;
        const ushort* src = (hl ? ql : qh) + (size_t)((tile ? s0gB : s0gA) + r) * 64 + c;
        *(uint4*)&Qs[tile][hl][r][c] = *(const uint4*)src;
    }
    __syncthreads();
    const ushort* khb = kh + ((size_t)b << 11) * 64;
    const ushort* klb = kl + ((size_t)b << 11) * 64;
    int ntA = (jA >> 1) + 1, ntB = (jB >> 1) + 1;
    int nAs = (ntA > s) ? (((ntA - 1 - s) >> 2) + 1) : 0;
    int nBs = (ntB > s) ? (((ntB - 1 - s) >> 2) + 1) : 0;
    int ntot = nAs + nBs;
    const floatx4 z4 = {0.f, 0.f, 0.f, 0.f};
    float llA[2][4] = {{0.f,0.f,0.f,0.f},{0.f,0.f,0.f,0.f}};
    float llB[2][4] = {{0.f,0.f,0.f,0.f},{0.f,0.f,0.f,0.f}};
    for (int it = wave; it < ntot; it += 4) {
        int isA = (it < nAs);
        int ti = isA ? (s + 4 * it) : (s + 4 * (it - nAs));
        int srow = isA ? srowA : srowB;
        int s0g = isA ? s0gA : s0gB;
        int tidx = isA ? 0 : 1;
        int k0 = ti << 6;
        floatx4 acc[2][4];
        #pragma unroll
        for (int mi = 0; mi < 2; ++mi)
            #pragma unroll
            for (int ni = 0; ni < 4; ++ni) acc[mi][ni] = z4;
        #pragma unroll
        for (int kk = 0; kk < 2; ++kk) {
            short8 ah0 = *(const short8*)&Qs[tidx][0][0 * 16 + m_][kk * 32 + qd * 8];
            short8 ah1 = *(const short8*)&Qs[tidx][0][1 * 16 + m_][kk * 32 + qd * 8];
            short8 al0 = *(const short8*)&Qs[tidx][1][0 * 16 + m_][kk * 32 + qd * 8];
            short8 al1 = *(const short8*)&Qs[tidx][1][1 * 16 + m_][kk * 32 + qd * 8];
            #pragma unroll
            for (int ni = 0; ni < 4; ++ni) {
                size_t koff = (size_t)(k0 + ni * 16 + m_) * 64 + kk * 32 + qd * 8;
                short8 bh = *(const short8*)&khb[koff];
                short8 bl = *(const short8*)&klb[koff];
                acc[0][ni] = __builtin_amdgcn_mfma_f32_16x16x32_bf16(ah0, bh, acc[0][ni], 0, 0, 0);
                acc[0][ni] = __builtin_amdgcn_mfma_f32_16x16x32_bf16(al0, bh, acc[0][ni], 0, 0, 0);
                acc[0][ni] = __builtin_amdgcn_mfma_f32_16x16x32_bf16(ah0, bl, acc[0][ni], 0, 0, 0);
                acc[1][ni] = __builtin_amdgcn_mfma_f32_16x16x32_bf16(ah1, bh, acc[1][ni], 0, 0, 0);
                acc[1][ni] = __builtin_amdgcn_mfma_f32_16x16x32_bf16(al1, bh, acc[1][ni], 0, 0, 0);
                acc[1][ni] = __builtin_amdgcn_mfma_f32_16x16x32_bf16(ah1, bl, acc[1][ni], 0, 0, 0);
            }
        }
        #pragma unroll
        for (int mi = 0; mi < 2; ++mi)
            #pragma unroll
            for (int ni = 0; ni < 4; ++ni) {
                int kc = k0 + ni * 16 + m_;
                #pragma unroll
                for (int r = 0; r < 4; ++r) {
                    int row = srow + mi * 16 + qd * 4 + r;
                    float p = (kc <= row) ? __expf(acc[mi][ni][r]) : 0.f;
                    if (isA) llA[mi][r] += p; else llB[mi][r] += p;
                    P[(size_t)(s0g + mi * 16 + qd * 4 + r) * 2048 + kc] = f2bf(p);
                }
            }
    }
    #pragma unroll
    for (int d = 1; d < 16; d <<= 1)
        #pragma unroll
        for (int mi = 0; mi < 2; ++mi)
            #pragma unroll
            for (int r = 0; r < 4; ++r) {
                llA[mi][r] += __shfl_xor(llA[mi][r], d);
                llB[mi][r] += __shfl_xor(llB[mi][r], d);
            }
    if (m_ == 0)
        #pragma unroll
        for (int mi = 0; mi < 2; ++mi)
            #pragma unroll
            for (int r = 0; r < 4; ++r) {
                lred[wave][0][mi * 16 + qd * 4 + r] = llA[mi][r];
                lred[wave][1][mi * 16 + qd * 4 + r] = llB[mi][r];
            }
    __syncthreads();
    if (t < 64) {
        int tile = t >> 5, row = t & 31;
        float sm = lred[0][tile][row] + lred[1][tile][row]
                 + lred[2][tile][row] + lred[3][tile][row];
        lpart[(size_t)s * NROWS + (tile ? s0gB : s0gA) + row] = sm;
    }
}

// ---------------- K4: Axv_part = P~ @ xv (paired m-tiles, 8-way k-split) ----------------
// Block = (pair p, b, split s): long m-tile 31-p + short m-tile p share the
// B tile (xv k-slab). BK=64 double-buffered swizzled LDS via global_load_lds.
__global__ __launch_bounds__(256) void pv_kernel(
    const ushort* __restrict__ P, const ushort* __restrict__ xvhT,
    float* __restrict__ AxvPart)
{
    __shared__ __align__(16) ushort AL[2][64 * 64];
    __shared__ __align__(16) ushort AS[2][64 * 64];
    __shared__ __align__(16) ushort Bs[2][64 * 64];
    int bid = blockIdx.x;
    int p = bid >> 5;                // 0..15
    int b = (bid >> 3) & 3;
    int s = bid & 7;
    int m0L = (31 - p) << 6, m0S = p << 6;
    int ntL = 32 - p, ntS = p + 1;
    int nL = (ntL - s + 7) >> 3;                         // ntL >= 17 > s
    int nS = (ntS > s) ? ((ntS - s + 7) >> 3) : 0;
    int t = threadIdx.x, wave = t >> 6, lane = t & 63, m_ = lane & 15, qd = lane >> 4;
    const ushort* Pb = P + ((size_t)b << 22);
    const ushort* Xb = xvhT + ((size_t)(b * 64) << 11);
    const floatx4 z4 = {0.f, 0.f, 0.f, 0.f};
    floatx4 accL[2][2], accS[2][2];
    #pragma unroll
    for (int mi = 0; mi < 2; ++mi)
        #pragma unroll
        for (int ni = 0; ni < 2; ++ni) { accL[mi][ni] = z4; accS[mi][ni] = z4; }
    int mb = (wave >> 1) << 5;       // 0 / 32 (P rows in tile)
    int nb = (wave & 1) << 5;        // 0 / 32 (h cols)
    int drow = lane >> 3;                      // 0..7
    int dlc = ((lane & 7) ^ drow) << 3;        // pre-swizzled 16B chunk
    // stage 24 instrs: 0..7 AL, 8..15 Bs(xv), 16..23 AS (if tile active); wave does 6
    #define PV_STAGE(tt, buf)                                                    \
        {                                                                        \
            int k0_ = (s + 8 * (tt)) << 6;                                       \
            _Pragma("unroll")                                                    \
            for (int i_ = 0; i_ < 6; ++i_) {                                     \
                int c_ = wave * 6 + i_;                                          \
                if (c_ < 8)                                                      \
                    load_lds16(Pb + (size_t)(m0L + c_ * 8 + drow) * SEQ + k0_ + dlc, \
                               &AL[buf][c_ * 512]);                              \
                else if (c_ < 16)                                                \
                    load_lds16(Xb + (size_t)((c_ - 8) * 8 + drow) * SEQ + k0_ + dlc, \
                               &Bs[buf][(c_ - 8) * 512]);                        \
                else if ((tt) < nS)                                              \
                    load_lds16(Pb + (size_t)(m0S + (c_ - 16) * 8 + drow) * SEQ + k0_ + dlc, \
                               &AS[buf][(c_ - 16) * 512]);                       \
            }                                                                    \
        }
    PV_STAGE(0, 0)
    for (int tt = 0; tt < nL; ++tt) {
        __syncthreads();
        if (tt + 1 < nL) PV_STAGE(tt + 1, (tt + 1) & 1)
        int bufi = tt & 1;
        #pragma unroll
        for (int kk = 0; kk < 2; ++kk) {
            short8 bb[2];
            #pragma unroll
            for (int ni = 0; ni < 2; ++ni) {
                int row = nb + ni * 16 + m_;
                bb[ni] = *(const short8*)&Bs[bufi][row * 64 + (((kk << 2) + qd) ^ (row & 7)) * 8];
            }
            #pragma unroll
            for (int mi = 0; mi < 2; ++mi) {
                int row = mb + mi * 16 + m_;
                short8 aL = *(const short8*)&AL[bufi][row * 64 + (((kk << 2) + qd) ^ (row & 7)) * 8];
                #pragma unroll
                for (int ni = 0; ni < 2; ++ni)
                    accL[mi][ni] = __builtin_amdgcn_mfma_f32_16x16x32_bf16(aL, bb[ni], accL[mi][ni], 0, 0, 0);
            }
            if (tt < nS) {
                #pragma unroll
                for (int mi = 0; mi < 2; ++mi) {
                    int row = mb + mi * 16 + m_;
                    short8 aS = *(const short8*)&AS[bufi][row * 64 + (((kk << 2) + qd) ^ (row & 7)) * 8];
                    #pragma unroll
                    for (int ni = 0; ni < 2; ++ni)
                        accS[mi][ni] = __builtin_amdgcn_mfma_f32_16x16x32_bf16(aS, bb[ni], accS[mi][ni], 0, 0, 0);
                }
            }
        }
    }
    float* Ap = AxvPart + (size_t)s * (NROWS * DH);
    #pragma unroll
    for (int mi = 0; mi < 2; ++mi) {
        #pragma unroll
        for (int r = 0; r < 4; ++r) {
            int rowL = m0L + mb + mi * 16 + qd * 4 + r;
            int rowS = m0S + mb + mi * 16 + qd * 4 + r;
            float* orL = Ap + (size_t)((b << 11) + rowL) * DH + nb;
            float* orS = Ap + (size_t)((b << 11) + rowS) * DH + nb;
            #pragma unroll
            for (int ni = 0; ni < 2; ++ni) {
                orL[ni * 16 + m_] = accL[mi][ni][r];
                orS[ni * 16 + m_] = accS[mi][ni][r];   // zeros if no short tiles
            }
        }
    }
    #undef PV_STAGE
}

// ---------------- K5: out = (reduce(Axv_part) * 1/l) @ O^T ----------------
// Block = 64 rows x 128 e-cols. A = Axv hi/lo, B = O hi/lo (converted on load).
__global__ __launch_bounds__(256) void out_kernel(
    const float* __restrict__ AxvPart, const float* __restrict__ lpart,
    const float* __restrict__ O, float* __restrict__ out)
{
    __shared__ __align__(16) ushort As[2][64][72];
    __shared__ __align__(16) ushort Bsh[2][128][72];
    __shared__ float lsc[64];
    int bid = blockIdx.x;
    int r0 = (bid >> 3) << 6;        // global row 0..8128
    int e0 = (bid & 7) << 7;         // 0..896
    int t = threadIdx.x;
    if (t < 64) {
        int rg = r0 + t;
        lsc[t] = 1.f / (lpart[rg] + lpart[NROWS + rg]
                      + lpart[2 * NROWS + rg] + lpart[3 * NROWS + rg]);
    }
    __syncthreads();
    const size_t PSL = (size_t)NROWS * DH;
    #pragma unroll
    for (int i = 0; i < 16; ++i) {
        int idx = i * 256 + t;
        int r = idx >> 6, h = idx & 63;
        size_t off = (size_t)(r0 + r) * DH + h;
        float a = 0.f;
        #pragma unroll
        for (int sp = 0; sp < PVSPLIT; ++sp) a += AxvPart[sp * PSL + off];
        a *= lsc[r];
        ushort hi = f2bf(a);
        As[0][r][h] = hi;
        As[1][r][h] = f2bf(a - bf2f(hi));
    }
    #pragma unroll
    for (int i = 0; i < 32; ++i) {
        int idx = i * 256 + t;
        int r = idx >> 6, h = idx & 63;
        float w = O[(size_t)(e0 + r) * DH + h];
        ushort hi = f2bf(w);
        Bsh[0][r][h] = hi;
        Bsh[1][r][h] = f2bf(w - bf2f(hi));
    }
    __syncthreads();
    int wave = t >> 6, lane = t & 63, m_ = lane & 15, qd = lane >> 4;
    const floatx4 z4 = {0.f, 0.f, 0.f, 0.f};
    floatx4 acc[8] = {z4, z4, z4, z4, z4, z4, z4, z4};
    #pragma unroll
    for (int kk = 0; kk < 2; ++kk) {
        short8 ah = *(const short8*)&As[0][wave * 16 + m_][kk * 32 + qd * 8];
        short8 al = *(const short8*)&As[1][wave * 16 + m_][kk * 32 + qd * 8];
        #pragma unroll
        for (int ni = 0; ni < 8; ++ni) {
            short8 bh = *(const short8*)&Bsh[0][ni * 16 + m_][kk * 32 + qd * 8];
            short8 bl = *(const short8*)&Bsh[1][ni * 16 + m_][kk * 32 + qd * 8];
            acc[ni] = __builtin_amdgcn_mfma_f32_16x16x32_bf16(ah, bh, acc[ni], 0, 0, 0);
            acc[ni] = __builtin_amdgcn_mfma_f32_16x16x32_bf16(al, bh, acc[ni], 0, 0, 0);
            acc[ni] = __builtin_amdgcn_mfma_f32_16x16x32_bf16(ah, bl, acc[ni], 0, 0, 0);
        }
    }
    #pragma unroll
    for (int r = 0; r < 4; ++r) {
        int row = r0 + wave * 16 + qd * 4 + r;
        float* orow = out + (size_t)row * DM + e0;
        #pragma unroll
        for (int ni = 0; ni < 8; ++ni)
            orow[ni * 16 + m_] = acc[ni][r];
    }
}

extern "C" void kernel_launch(void* const* d_in, const int* in_sizes, int n_in,
                              void* d_out, int out_size, void* d_ws, size_t ws_size,
                              hipStream_t stream) {
    const float* x = (const float*)d_in[0];
    const float* Q = (const float*)d_in[1];
    const float* K = (const float*)d_in[2];
    const float* V = (const float*)d_in[3];
    const float* O = (const float*)d_in[4];
    float* out = (float*)d_out;

    char* ws = (char*)d_ws;
    ushort* qh   = (ushort*)(ws);                    // 1 MB [8192][64] bf16
    ushort* ql   = (ushort*)(ws + (1ull  << 20));
    ushort* kh   = (ushort*)(ws + (2ull  << 20));
    ushort* kl   = (ushort*)(ws + (3ull  << 20));
    ushort* xvhT = (ushort*)(ws + (4ull  << 20));    // 1 MB [4*64][2048] bf16 (xv transposed)
    ushort* WhT  = (ushort*)(ws + (5ull  << 20));    // 384 KB [192][1024]
    ushort* WlT  = (ushort*)(ws + (5ull  << 20) + (512ull << 10));
    float*  lpart = (float*)(ws + (6ull  << 20));    // 128 KB [4][8192]
    float*  AxvPart = (float*)(ws + (7ull << 20));   // 16 MB [8][8192][64] fp32
    ushort* Pbuf = (ushort*)(ws + (23ull << 20));    // 32 MB [8192][2048]
    float*  Cpart = (float*)(ws + (23ull << 20));    // 25 MB, overlaps Pbuf (dead before K3)

    wprep_kernel<<<192, 256, 0, stream>>>(Q, K, V, WhT, WlT);
    qkv_part_kernel<<<dim3(NROWS / 32, 4), 256, 0, stream>>>(x, WhT, WlT, Cpart);
    qkv_reduce_kernel<<<NROWS / 32, 256, 0, stream>>>(Cpart, qh, ql, kh, kl, xvhT);
    softmax_kernel<<<dim3(32 * BATCH, 4), 256, 0, stream>>>(qh, ql, kh, kl, Pbuf, lpart);
    pv_kernel<<<16 * 4 * PVSPLIT, 256, 0, stream>>>(Pbuf, xvhT, AxvPart);
    out_kernel<<<(NROWS / 64) * 8, 256, 0, stream>>>(AxvPart, lpart, O, out);
}

// Round 2
// 162.050 us; speedup vs baseline: 1.1208x; 1.1208x over previous
//
#include <hip/hip_runtime.h>
#include <hip/hip_bf16.h>
#include <math.h>

// MyAttentionHead: B=4, S=2048, d_model=1024, d_head=64. fp32 in/out storage.
// out = ((P~ @ xv) * 1/l) @ O^T  (associativity rewrite).
// K0 wprep (QKV hi/lo transposed + O hi/lo), K1a qkv_part MFMA (K-split 4),
// K1b qkv_reduce (+xv transpose), K3 softmax MFMA (paired q-tiles, 4-way k-split,
// unnormalized P~), K4 pv: Axv_part = P~ @ xv (paired m-tiles, 8-way k-split),
// K4b axv_reduce: fold splits + 1/l scale -> bf16 hi/lo (reads partials ONCE),
// K5 out: bf16 hi/lo GEMM [8192,64]@[64,1024] -> fp32 out (write-bound).
#define BATCH 4
#define SEQ   2048
#define DM    1024
#define DH    64
#define NROWS (BATCH*SEQ)   // 8192
#define PVSPLIT 8

typedef __hip_bfloat16 bf16;
typedef __attribute__((ext_vector_type(8))) short short8;
typedef __attribute__((ext_vector_type(8))) unsigned short ushortx8;
typedef __attribute__((ext_vector_type(4))) float floatx4;

__device__ __forceinline__ ushort f2bf(float f) {
    union { bf16 h; ushort u; } cv;
    cv.h = __float2bfloat16(f);
    return cv.u;
}
__device__ __forceinline__ float bf2f(ushort u) {
    union { unsigned int i; float f; } v; v.i = ((unsigned int)u) << 16; return v.f;
}

// async 16B global->LDS: lds dest = wave-uniform base + lane*16
__device__ __forceinline__ void load_lds16(const ushort* g, ushort* l) {
    __builtin_amdgcn_global_load_lds(
        (const __attribute__((address_space(1))) unsigned int*)g,
        (__attribute__((address_space(3))) unsigned int*)l, 16, 0, 0);
}

// ---------------- K0: weight prep ----------------
// blocks 0..191: QKV columns -> WhT/WlT [192][1024] (transposed, hi/lo).
// blocks 192..255: O rows -> Oh/Ol [1024][64] (natural layout, hi/lo).
__global__ __launch_bounds__(256) void wprep_kernel(
    const float* __restrict__ Q, const float* __restrict__ K,
    const float* __restrict__ V, const float* __restrict__ O,
    ushort* __restrict__ WhT, ushort* __restrict__ WlT,
    ushort* __restrict__ Oh, ushort* __restrict__ Ol)
{
    int n = blockIdx.x;                       // 0..255
    if (n < 192) {
        const float* W = (n < 64) ? Q : (n < 128) ? K : V;
        int c = n & 63;
        for (int k = threadIdx.x; k < DM; k += 256) {
            float w = W[k * DH + c];
            ushort hi = f2bf(w);
            WhT[n * DM + k] = hi;
            WlT[n * DM + k] = f2bf(w - bf2f(hi));
        }
    } else {
        int e0 = (n - 192) << 4;              // 16 rows of O per block
        for (int idx = threadIdx.x; idx < 16 * DH; idx += 256) {
            int off = (e0 << 6) + idx;
            float w = O[off];
            ushort hi = f2bf(w);
            Oh[off] = hi;
            Ol[off] = f2bf(w - bf2f(hi));
        }
    }
}

// ---------------- K1a: qkv partial MFMA (K-split 4) ----------------
__global__ __launch_bounds__(256) void qkv_part_kernel(
    const float* __restrict__ x, const ushort* __restrict__ WhT,
    const ushort* __restrict__ WlT, float* __restrict__ Cpart)
{
    __shared__ __align__(16) ushort Xs[2][32][34];
    __shared__ __align__(16) ushort Ws[2][192][34];
    int s0 = blockIdx.x * 32;
    int kb = blockIdx.y * 256;
    int t = threadIdx.x;
    int wave = t >> 6, lane = t & 63, m_ = lane & 15, qd = lane >> 4;
    const floatx4 z4 = {0.f, 0.f, 0.f, 0.f};
    floatx4 accq[2] = {z4, z4}, acck[2] = {z4, z4}, accv[2] = {z4, z4};
    int xr = t >> 3, xc = (t & 7) * 4;
    for (int k0 = 0; k0 < 256; k0 += 32) {
        float4 v = *(const float4*)&x[(size_t)(s0 + xr) * DM + kb + k0 + xc];
        ushort h0 = f2bf(v.x), h1 = f2bf(v.y), h2 = f2bf(v.z), h3 = f2bf(v.w);
        *(ushort4*)&Xs[0][xr][xc] = make_ushort4(h0, h1, h2, h3);
        *(ushort4*)&Xs[1][xr][xc] = make_ushort4(
            f2bf(v.x - bf2f(h0)), f2bf(v.y - bf2f(h1)),
            f2bf(v.z - bf2f(h2)), f2bf(v.w - bf2f(h3)));
        #pragma unroll
        for (int j = 0; j < 3; ++j) {
            int idx = t + j * 256, n = idx >> 2, kc = (idx & 3) * 8;
            *(uint4*)&Ws[0][n][kc] = *(const uint4*)&WhT[n * DM + kb + k0 + kc];
            *(uint4*)&Ws[1][n][kc] = *(const uint4*)&WlT[n * DM + kb + k0 + kc];
        }
        __syncthreads();
        short8 ah[2], al[2];
        #pragma unroll
        for (int mi = 0; mi < 2; ++mi) {
            ah[mi] = *(const short8*)&Xs[0][mi * 16 + m_][qd * 8];
            al[mi] = *(const short8*)&Xs[1][mi * 16 + m_][qd * 8];
        }
        int nq = wave * 16 + m_, nk = 64 + wave * 16 + m_, nv = 128 + wave * 16 + m_;
        short8 bqh = *(const short8*)&Ws[0][nq][qd * 8];
        short8 bql = *(const short8*)&Ws[1][nq][qd * 8];
        short8 bkh = *(const short8*)&Ws[0][nk][qd * 8];
        short8 bkl = *(const short8*)&Ws[1][nk][qd * 8];
        short8 bvh = *(const short8*)&Ws[0][nv][qd * 8];
        #pragma unroll
        for (int mi = 0; mi < 2; ++mi) {
            accq[mi] = __builtin_amdgcn_mfma_f32_16x16x32_bf16(ah[mi], bqh, accq[mi], 0, 0, 0);
            accq[mi] = __builtin_amdgcn_mfma_f32_16x16x32_bf16(al[mi], bqh, accq[mi], 0, 0, 0);
            accq[mi] = __builtin_amdgcn_mfma_f32_16x16x32_bf16(ah[mi], bql, accq[mi], 0, 0, 0);
            acck[mi] = __builtin_amdgcn_mfma_f32_16x16x32_bf16(ah[mi], bkh, acck[mi], 0, 0, 0);
            acck[mi] = __builtin_amdgcn_mfma_f32_16x16x32_bf16(al[mi], bkh, acck[mi], 0, 0, 0);
            acck[mi] = __builtin_amdgcn_mfma_f32_16x16x32_bf16(ah[mi], bkl, acck[mi], 0, 0, 0);
            accv[mi] = __builtin_amdgcn_mfma_f32_16x16x32_bf16(ah[mi], bvh, accv[mi], 0, 0, 0);
        }
        __syncthreads();
    }
    float* Cp = Cpart + (size_t)blockIdx.y * (NROWS * 192);
    #pragma unroll
    for (int mi = 0; mi < 2; ++mi) {
        #pragma unroll
        for (int r = 0; r < 4; ++r) {
            int row = s0 + mi * 16 + qd * 4 + r;
            float* base = Cp + (size_t)row * 192;
            base[wave * 16 + m_]       = accq[mi][r];
            base[64 + wave * 16 + m_]  = acck[mi][r];
            base[128 + wave * 16 + m_] = accv[mi][r];
        }
    }
}

// ---------------- K1b: reduce partials, split hi/lo, transpose xv ----------------
__global__ __launch_bounds__(256) void qkv_reduce_kernel(
    const float* __restrict__ Cpart,
    ushort* __restrict__ qh, ushort* __restrict__ ql,
    ushort* __restrict__ kh, ushort* __restrict__ kl, ushort* __restrict__ xvhT)
{
    __shared__ ushort xvs[32][72];
    const size_t SL = (size_t)NROWS * 192;
    int row0 = blockIdx.x * 32;
    int t = threadIdx.x;
    #pragma unroll
    for (int i = 0; i < 24; ++i) {
        int e = i * 256 + t;
        int r = e / 192, c = e - r * 192;
        size_t row = row0 + r;
        size_t off = row * 192 + c;
        float s = Cpart[off] + Cpart[SL + off] + Cpart[2 * SL + off] + Cpart[3 * SL + off];
        ushort hi = f2bf(s);
        if (c < 64) {
            qh[row * 64 + c] = hi; ql[row * 64 + c] = f2bf(s - bf2f(hi));
        } else if (c < 128) {
            kh[row * 64 + c - 64] = hi; kl[row * 64 + c - 64] = f2bf(s - bf2f(hi));
        } else {
            xvs[r][c - 128] = hi;
        }
    }
    __syncthreads();
    int h = t >> 2, seg = t & 3;          // 64 h-rows x 4 segments of 8 s
    ushortx8 v;
    #pragma unroll
    for (int k = 0; k < 8; ++k) v[k] = xvs[seg * 8 + k][h];
    int b = row0 >> 11, sl = row0 & 2047;
    *(ushortx8*)&xvhT[(((size_t)(b * 64 + h)) << 11) + sl + seg * 8] = v;
}

// ---------------- K3: softmax MFMA, paired q-tiles + 4-way k-split ----------------
__global__ __launch_bounds__(256) void softmax_kernel(
    const ushort* __restrict__ qh, const ushort* __restrict__ ql,
    const ushort* __restrict__ kh, const ushort* __restrict__ kl,
    ushort* __restrict__ P, float* __restrict__ lpart)
{
    __shared__ __align__(16) ushort Qs[2][2][32][72];  // [tile][hi/lo][row][col]
    __shared__ float lred[4][2][32];
    int pp = blockIdx.x & 31, b = blockIdx.x >> 5, s = blockIdx.y;
    int jA = pp, jB = 63 - pp;
    int srowA = jA << 5, srowB = jB << 5;
    int s0gA = (b << 11) + srowA, s0gB = (b << 11) + srowB;
    int t = threadIdx.x, wave = t >> 6, lane = t & 63, m_ = lane & 15, qd = lane >> 4;
    #pragma unroll
    for (int i = 0; i < 4; ++i) {
        int idx = i * 256 + t;
        int tile = idx >> 9, hl = (idx >> 8) & 1, r = (idx >> 3) & 31, c = (idx & 7) * 8;
        const ushort* src = (hl ? ql : qh) + (size_t)((tile ? s0gB : s0gA) + r) * 64 + c;
        *(uint4*)&Qs[tile][hl][r][c] = *(const uint4*)src;
    }
    __syncthreads();
    const ushort* khb = kh + ((size_t)b << 11) * 64;
    const ushort* klb = kl + ((size_t)b << 11) * 64;
    int ntA = (jA >> 1) + 1, ntB = (jB >> 1) + 1;
    int nAs = (ntA > s) ? (((ntA - 1 - s) >> 2) + 1) : 0;
    int nBs = (ntB > s) ? (((ntB - 1 - s) >> 2) + 1) : 0;
    int ntot = nAs + nBs;
    const floatx4 z4 = {0.f, 0.f, 0.f, 0.f};
    float llA[2][4] = {{0.f,0.f,0.f,0.f},{0.f,0.f,0.f,0.f}};
    float llB[2][4] = {{0.f,0.f,0.f,0.f},{0.f,0.f,0.f,0.f}};
    for (int it = wave; it < ntot; it += 4) {
        int isA = (it < nAs);
        int ti = isA ? (s + 4 * it) : (s + 4 * (it - nAs));
        int srow = isA ? srowA : srowB;
        int s0g = isA ? s0gA : s0gB;
        int tidx = isA ? 0 : 1;
        int k0 = ti << 6;
        floatx4 acc[2][4];
        #pragma unroll
        for (int mi = 0; mi < 2; ++mi)
            #pragma unroll
            for (int ni = 0; ni < 4; ++ni) acc[mi][ni] = z4;
        #pragma unroll
        for (int kk = 0; kk < 2; ++kk) {
            short8 ah0 = *(const short8*)&Qs[tidx][0][0 * 16 + m_][kk * 32 + qd * 8];
            short8 ah1 = *(const short8*)&Qs[tidx][0][1 * 16 + m_][kk * 32 + qd * 8];
            short8 al0 = *(const short8*)&Qs[tidx][1][0 * 16 + m_][kk * 32 + qd * 8];
            short8 al1 = *(const short8*)&Qs[tidx][1][1 * 16 + m_][kk * 32 + qd * 8];
            #pragma unroll
            for (int ni = 0; ni < 4; ++ni) {
                size_t koff = (size_t)(k0 + ni * 16 + m_) * 64 + kk * 32 + qd * 8;
                short8 bh = *(const short8*)&khb[koff];
                short8 bl = *(const short8*)&klb[koff];
                acc[0][ni] = __builtin_amdgcn_mfma_f32_16x16x32_bf16(ah0, bh, acc[0][ni], 0, 0, 0);
                acc[0][ni] = __builtin_amdgcn_mfma_f32_16x16x32_bf16(al0, bh, acc[0][ni], 0, 0, 0);
                acc[0][ni] = __builtin_amdgcn_mfma_f32_16x16x32_bf16(ah0, bl, acc[0][ni], 0, 0, 0);
                acc[1][ni] = __builtin_amdgcn_mfma_f32_16x16x32_bf16(ah1, bh, acc[1][ni], 0, 0, 0);
                acc[1][ni] = __builtin_amdgcn_mfma_f32_16x16x32_bf16(al1, bh, acc[1][ni], 0, 0, 0);
                acc[1][ni] = __builtin_amdgcn_mfma_f32_16x16x32_bf16(ah1, bl, acc[1][ni], 0, 0, 0);
            }
        }
        #pragma unroll
        for (int mi = 0; mi < 2; ++mi)
            #pragma unroll
            for (int ni = 0; ni < 4; ++ni) {
                int kc = k0 + ni * 16 + m_;
                #pragma unroll
                for (int r = 0; r < 4; ++r) {
                    int row = srow + mi * 16 + qd * 4 + r;
                    float p = (kc <= row) ? __expf(acc[mi][ni][r]) : 0.f;
                    if (isA) llA[mi][r] += p; else llB[mi][r] += p;
                    P[(size_t)(s0g + mi * 16 + qd * 4 + r) * 2048 + kc] = f2bf(p);
                }
            }
    }
    #pragma unroll
    for (int d = 1; d < 16; d <<= 1)
        #pragma unroll
        for (int mi = 0; mi < 2; ++mi)
            #pragma unroll
            for (int r = 0; r < 4; ++r) {
                llA[mi][r] += __shfl_xor(llA[mi][r], d);
                llB[mi][r] += __shfl_xor(llB[mi][r], d);
            }
    if (m_ == 0)
        #pragma unroll
        for (int mi = 0; mi < 2; ++mi)
            #pragma unroll
            for (int r = 0; r < 4; ++r) {
                lred[wave][0][mi * 16 + qd * 4 + r] = llA[mi][r];
                lred[wave][1][mi * 16 + qd * 4 + r] = llB[mi][r];
            }
    __syncthreads();
    if (t < 64) {
        int tile = t >> 5, row = t & 31;
        float sm = lred[0][tile][row] + lred[1][tile][row]
                 + lred[2][tile][row] + lred[3][tile][row];
        lpart[(size_t)s * NROWS + (tile ? s0gB : s0gA) + row] = sm;
    }
}

// ---------------- K4: Axv_part = P~ @ xv (paired m-tiles, 8-way k-split) ----------------
__global__ __launch_bounds__(256) void pv_kernel(
    const ushort* __restrict__ P, const ushort* __restrict__ xvhT,
    float* __restrict__ AxvPart)
{
    __shared__ __align__(16) ushort AL[2][64 * 64];
    __shared__ __align__(16) ushort AS[2][64 * 64];
    __shared__ __align__(16) ushort Bs[2][64 * 64];
    int bid = blockIdx.x;
    int p = bid >> 5;                // 0..15
    int b = (bid >> 3) & 3;
    int s = bid & 7;
    int m0L = (31 - p) << 6, m0S = p << 6;
    int ntL = 32 - p, ntS = p + 1;
    int nL = (ntL - s + 7) >> 3;                         // ntL >= 17 > s
    int nS = (ntS > s) ? ((ntS - s + 7) >> 3) : 0;
    int t = threadIdx.x, wave = t >> 6, lane = t & 63, m_ = lane & 15, qd = lane >> 4;
    const ushort* Pb = P + ((size_t)b << 22);
    const ushort* Xb = xvhT + ((size_t)(b * 64) << 11);
    const floatx4 z4 = {0.f, 0.f, 0.f, 0.f};
    floatx4 accL[2][2], accS[2][2];
    #pragma unroll
    for (int mi = 0; mi < 2; ++mi)
        #pragma unroll
        for (int ni = 0; ni < 2; ++ni) { accL[mi][ni] = z4; accS[mi][ni] = z4; }
    int mb = (wave >> 1) << 5;       // 0 / 32 (P rows in tile)
    int nb = (wave & 1) << 5;        // 0 / 32 (h cols)
    int drow = lane >> 3;                      // 0..7
    int dlc = ((lane & 7) ^ drow) << 3;        // pre-swizzled 16B chunk
    // stage 24 instrs: 0..7 AL, 8..15 Bs(xv), 16..23 AS (if tile active); wave does 6
    #define PV_STAGE(tt, buf)                                                    \
        {                                                                        \
            int k0_ = (s + 8 * (tt)) << 6;                                       \
            _Pragma("unroll")                                                    \
            for (int i_ = 0; i_ < 6; ++i_) {                                     \
                int c_ = wave * 6 + i_;                                          \
                if (c_ < 8)                                                      \
                    load_lds16(Pb + (size_t)(m0L + c_ * 8 + drow) * SEQ + k0_ + dlc, \
                               &AL[buf][c_ * 512]);                              \
                else if (c_ < 16)                                                \
                    load_lds16(Xb + (size_t)((c_ - 8) * 8 + drow) * SEQ + k0_ + dlc, \
                               &Bs[buf][(c_ - 8) * 512]);                        \
                else if ((tt) < nS)                                              \
                    load_lds16(Pb + (size_t)(m0S + (c_ - 16) * 8 + drow) * SEQ + k0_ + dlc, \
                               &AS[buf][(c_ - 16) * 512]);                       \
            }                                                                    \
        }
    PV_STAGE(0, 0)
    for (int tt = 0; tt < nL; ++tt) {
        __syncthreads();
        if (tt + 1 < nL) PV_STAGE(tt + 1, (tt + 1) & 1)
        int bufi = tt & 1;
        #pragma unroll
        for (int kk = 0; kk < 2; ++kk) {
            short8 bb[2];
            #pragma unroll
            for (int ni = 0; ni < 2; ++ni) {
                int row = nb + ni * 16 + m_;
                bb[ni] = *(const short8*)&Bs[bufi][row * 64 + (((kk << 2) + qd) ^ (row & 7)) * 8];
            }
            #pragma unroll
            for (int mi = 0; mi < 2; ++mi) {
                int row = mb + mi * 16 + m_;
                short8 aL = *(const short8*)&AL[bufi][row * 64 + (((kk << 2) + qd) ^ (row & 7)) * 8];
                #pragma unroll
                for (int ni = 0; ni < 2; ++ni)
                    accL[mi][ni] = __builtin_amdgcn_mfma_f32_16x16x32_bf16(aL, bb[ni], accL[mi][ni], 0, 0, 0);
            }
            if (tt < nS) {
                #pragma unroll
                for (int mi = 0; mi < 2; ++mi) {
                    int row = mb + mi * 16 + m_;
                    short8 aS = *(const short8*)&AS[bufi][row * 64 + (((kk << 2) + qd) ^ (row & 7)) * 8];
                    #pragma unroll
                    for (int ni = 0; ni < 2; ++ni)
                        accS[mi][ni] = __builtin_amdgcn_mfma_f32_16x16x32_bf16(aS, bb[ni], accS[mi][ni], 0, 0, 0);
                }
            }
        }
    }
    float* Ap = AxvPart + (size_t)s * (NROWS * DH);
    #pragma unroll
    for (int mi = 0; mi < 2; ++mi) {
        #pragma unroll
        for (int r = 0; r < 4; ++r) {
            int rowL = m0L + mb + mi * 16 + qd * 4 + r;
            int rowS = m0S + mb + mi * 16 + qd * 4 + r;
            float* orL = Ap + (size_t)((b << 11) + rowL) * DH + nb;
            float* orS = Ap + (size_t)((b << 11) + rowS) * DH + nb;
            #pragma unroll
            for (int ni = 0; ni < 2; ++ni) {
                orL[ni * 16 + m_] = accL[mi][ni][r];
                orS[ni * 16 + m_] = accS[mi][ni][r];   // zeros if no short tiles
            }
        }
    }
    #undef PV_STAGE
}

// ---------------- K4b: reduce splits + scale -> bf16 hi/lo (reads partials once) ----------------
__global__ __launch_bounds__(256) void axv_reduce_kernel(
    const float* __restrict__ AxvPart, const float* __restrict__ lpart,
    ushort* __restrict__ Axvh, ushort* __restrict__ Axvl)
{
    const size_t PSL = (size_t)NROWS * DH;
    int idx = blockIdx.x * 256 + threadIdx.x;   // 131072 groups of 4
    size_t e = (size_t)idx * 4;
    int r = (int)(e >> 6);
    float4 a = *(const float4*)&AxvPart[e];
    #pragma unroll
    for (int sp = 1; sp < PVSPLIT; ++sp) {
        float4 v = *(const float4*)&AxvPart[sp * PSL + e];
        a.x += v.x; a.y += v.y; a.z += v.z; a.w += v.w;
    }
    float sc = 1.f / (lpart[r] + lpart[NROWS + r]
                    + lpart[2 * NROWS + r] + lpart[3 * NROWS + r]);
    a.x *= sc; a.y *= sc; a.z *= sc; a.w *= sc;
    ushort h0 = f2bf(a.x), h1 = f2bf(a.y), h2 = f2bf(a.z), h3 = f2bf(a.w);
    *(ushort4*)&Axvh[e] = make_ushort4(h0, h1, h2, h3);
    *(ushort4*)&Axvl[e] = make_ushort4(
        f2bf(a.x - bf2f(h0)), f2bf(a.y - bf2f(h1)),
        f2bf(a.z - bf2f(h2)), f2bf(a.w - bf2f(h3)));
}

// ---------------- K5: out = Axv @ O^T (bf16 hi/lo GEMM, write-bound) ----------------
// Block = 64 rows x 128 e-cols. All operands pre-converted bf16.
__global__ __launch_bounds__(256) void out_kernel(
    const ushort* __restrict__ Axvh, const ushort* __restrict__ Axvl,
    const ushort* __restrict__ Oh, const ushort* __restrict__ Ol,
    float* __restrict__ out)
{
    __shared__ __align__(16) ushort As[2][64][72];
    __shared__ __align__(16) ushort Bsh[2][128][72];
    int bid = blockIdx.x;
    int r0 = (bid >> 3) << 6;        // global row 0..8128
    int e0 = (bid & 7) << 7;         // 0..896
    int t = threadIdx.x;
    {   // A: 64 rows x 64 cols x 2 planes; 2 x uint4 per thread per plane
        int tr = t >> 2, tc = (t & 3) << 4;
        const ushort* ah = Axvh + (size_t)(r0 + tr) * DH + tc;
        const ushort* al = Axvl + (size_t)(r0 + tr) * DH + tc;
        *(uint4*)&As[0][tr][tc]     = *(const uint4*)ah;
        *(uint4*)&As[0][tr][tc + 8] = *(const uint4*)(ah + 8);
        *(uint4*)&As[1][tr][tc]     = *(const uint4*)al;
        *(uint4*)&As[1][tr][tc + 8] = *(const uint4*)(al + 8);
    }
    {   // B: 128 rows x 64 cols x 2 planes; 4 x uint4 per thread per plane
        int tr = t >> 1, tc = (t & 1) << 5;
        const ushort* bh = Oh + (size_t)(e0 + tr) * DH + tc;
        const ushort* bl = Ol + (size_t)(e0 + tr) * DH + tc;
        *(uint4*)&Bsh[0][tr][tc]      = *(const uint4*)bh;
        *(uint4*)&Bsh[0][tr][tc + 8]  = *(const uint4*)(bh + 8);
        *(uint4*)&Bsh[0][tr][tc + 16] = *(const uint4*)(bh + 16);
        *(uint4*)&Bsh[0][tr][tc + 24] = *(const uint4*)(bh + 24);
        *(uint4*)&Bsh[1][tr][tc]      = *(const uint4*)bl;
        *(uint4*)&Bsh[1][tr][tc + 8]  = *(const uint4*)(bl + 8);
        *(uint4*)&Bsh[1][tr][tc + 16] = *(const uint4*)(bl + 16);
        *(uint4*)&Bsh[1][tr][tc + 24] = *(const uint4*)(bl + 24);
    }
    __syncthreads();
    int wave = t >> 6, lane = t & 63, m_ = lane & 15, qd = lane >> 4;
    const floatx4 z4 = {0.f, 0.f, 0.f, 0.f};
    floatx4 acc[8] = {z4, z4, z4, z4, z4, z4, z4, z4};
    #pragma unroll
    for (int kk = 0; kk < 2; ++kk) {
        short8 ah = *(const short8*)&As[0][wave * 16 + m_][kk * 32 + qd * 8];
        short8 al = *(const short8*)&As[1][wave * 16 + m_][kk * 32 + qd * 8];
        #pragma unroll
        for (int ni = 0; ni < 8; ++ni) {
            short8 bh = *(const short8*)&Bsh[0][ni * 16 + m_][kk * 32 + qd * 8];
            short8 bl = *(const short8*)&Bsh[1][ni * 16 + m_][kk * 32 + qd * 8];
            acc[ni] = __builtin_amdgcn_mfma_f32_16x16x32_bf16(ah, bh, acc[ni], 0, 0, 0);
            acc[ni] = __builtin_amdgcn_mfma_f32_16x16x32_bf16(al, bh, acc[ni], 0, 0, 0);
            acc[ni] = __builtin_amdgcn_mfma_f32_16x16x32_bf16(ah, bl, acc[ni], 0, 0, 0);
        }
    }
    #pragma unroll
    for (int r = 0; r < 4; ++r) {
        int row = r0 + wave * 16 + qd * 4 + r;
        float* orow = out + (size_t)row * DM + e0;
        #pragma unroll
        for (int ni = 0; ni < 8; ++ni)
            orow[ni * 16 + m_] = acc[ni][r];
    }
}

extern "C" void kernel_launch(void* const* d_in, const int* in_sizes, int n_in,
                              void* d_out, int out_size, void* d_ws, size_t ws_size,
                              hipStream_t stream) {
    const float* x = (const float*)d_in[0];
    const float* Q = (const float*)d_in[1];
    const float* K = (const float*)d_in[2];
    const float* V = (const float*)d_in[3];
    const float* O = (const float*)d_in[4];
    float* out = (float*)d_out;

    char* ws = (char*)d_ws;
    ushort* qh   = (ushort*)(ws);                    // 1 MB [8192][64] bf16
    ushort* ql   = (ushort*)(ws + (1ull  << 20));
    ushort* kh   = (ushort*)(ws + (2ull  << 20));
    ushort* kl   = (ushort*)(ws + (3ull  << 20));
    ushort* xvhT = (ushort*)(ws + (4ull  << 20));    // 1 MB [4*64][2048] bf16 (xv transposed)
    ushort* WhT  = (ushort*)(ws + (5ull  << 20));    // 384 KB [192][1024]
    ushort* WlT  = (ushort*)(ws + (5ull  << 20) + (512ull << 10));
    float*  lpart = (float*)(ws + (6ull  << 20));    // 128 KB [4][8192]
    ushort* Oh   = (ushort*)(ws + (6ull  << 20) + (256ull << 10));  // 128 KB [1024][64]
    ushort* Ol   = (ushort*)(ws + (6ull  << 20) + (384ull << 10));  // 128 KB
    float*  AxvPart = (float*)(ws + (7ull << 20));   // 16 MB [8][8192][64] fp32
    ushort* Pbuf = (ushort*)(ws + (23ull << 20));    // 32 MB [8192][2048]
    float*  Cpart = (float*)(ws + (23ull << 20));    // 25 MB, overlaps Pbuf (dead before K3)
    // Axvh/Axvl overlap qh/ql (dead after softmax)
    ushort* Axvh = qh;
    ushort* Axvl = ql;

    wprep_kernel<<<256, 256, 0, stream>>>(Q, K, V, O, WhT, WlT, Oh, Ol);
    qkv_part_kernel<<<dim3(NROWS / 32, 4), 256, 0, stream>>>(x, WhT, WlT, Cpart);
    qkv_reduce_kernel<<<NROWS / 32, 256, 0, stream>>>(Cpart, qh, ql, kh, kl, xvhT);
    softmax_kernel<<<dim3(32 * BATCH, 4), 256, 0, stream>>>(qh, ql, kh, kl, Pbuf, lpart);
    pv_kernel<<<16 * 4 * PVSPLIT, 256, 0, stream>>>(Pbuf, xvhT, AxvPart);
    axv_reduce_kernel<<<NROWS * DH / 4 / 256, 256, 0, stream>>>(AxvPart, lpart, Axvh, Axvl);
    out_kernel<<<(NROWS / 64) * 8, 256, 0, stream>>>(Axvh, Axvl, Oh, Ol, out);
}

// Round 3
// 152.738 us; speedup vs baseline: 1.1891x; 1.0610x over previous
//
#include <hip/hip_runtime.h>
#include <hip/hip_bf16.h>
#include <math.h>

// MyAttentionHead: B=4, S=2048, d_model=1024, d_head=64. fp32 in/out storage.
// out = ((P~ @ xv) * 1/l) @ O^T  with FUSED flash-style attention:
// K0 wprep (QKV hi/lo transposed + O hi/lo), K1a qkv_part MFMA (K-split 4),
// K1b qkv_reduce (+xv PERMUTED to MFMA-B-fragment order xvP),
// K2 attn: fused S^T=mfma(K,Q) -> exp -> in-register P fragment -> PV mfma
//    (paired 16-row q-tiles (j,127-j): 33-34 uniform 64k-chunks/block,
//     8 waves share the chunk list; O and l finalized in-kernel -> Axv hi/lo),
// K3 out: bf16 hi/lo GEMM [8192,64]@[64,1024] -> fp32 out (write-bound).
#define BATCH 4
#define SEQ   2048
#define DM    1024
#define DH    64
#define NROWS (BATCH*SEQ)   // 8192

typedef __hip_bfloat16 bf16;
typedef __attribute__((ext_vector_type(8))) short short8;
typedef __attribute__((ext_vector_type(8))) unsigned short ushortx8;
typedef __attribute__((ext_vector_type(4))) float floatx4;

__device__ __forceinline__ ushort f2bf(float f) {
    union { bf16 h; ushort u; } cv;
    cv.h = __float2bfloat16(f);
    return cv.u;
}
__device__ __forceinline__ float bf2f(ushort u) {
    union { unsigned int i; float f; } v; v.i = ((unsigned int)u) << 16; return v.f;
}

// ---------------- K0: weight prep ----------------
__global__ __launch_bounds__(256) void wprep_kernel(
    const float* __restrict__ Q, const float* __restrict__ K,
    const float* __restrict__ V, const float* __restrict__ O,
    ushort* __restrict__ WhT, ushort* __restrict__ WlT,
    ushort* __restrict__ Oh, ushort* __restrict__ Ol)
{
    int n = blockIdx.x;                       // 0..255
    if (n < 192) {
        const float* W = (n < 64) ? Q : (n < 128) ? K : V;
        int c = n & 63;
        for (int k = threadIdx.x; k < DM; k += 256) {
            float w = W[k * DH + c];
            ushort hi = f2bf(w);
            WhT[n * DM + k] = hi;
            WlT[n * DM + k] = f2bf(w - bf2f(hi));
        }
    } else {
        int e0 = (n - 192) << 4;              // 16 rows of O per block
        for (int idx = threadIdx.x; idx < 16 * DH; idx += 256) {
            int off = (e0 << 6) + idx;
            float w = O[off];
            ushort hi = f2bf(w);
            Oh[off] = hi;
            Ol[off] = f2bf(w - bf2f(hi));
        }
    }
}

// ---------------- K1a: qkv partial MFMA (K-split 4) ----------------
__global__ __launch_bounds__(256) void qkv_part_kernel(
    const float* __restrict__ x, const ushort* __restrict__ WhT,
    const ushort* __restrict__ WlT, float* __restrict__ Cpart)
{
    __shared__ __align__(16) ushort Xs[2][32][34];
    __shared__ __align__(16) ushort Ws[2][192][34];
    int s0 = blockIdx.x * 32;
    int kb = blockIdx.y * 256;
    int t = threadIdx.x;
    int wave = t >> 6, lane = t & 63, m_ = lane & 15, qd = lane >> 4;
    const floatx4 z4 = {0.f, 0.f, 0.f, 0.f};
    floatx4 accq[2] = {z4, z4}, acck[2] = {z4, z4}, accv[2] = {z4, z4};
    int xr = t >> 3, xc = (t & 7) * 4;
    for (int k0 = 0; k0 < 256; k0 += 32) {
        float4 v = *(const float4*)&x[(size_t)(s0 + xr) * DM + kb + k0 + xc];
        ushort h0 = f2bf(v.x), h1 = f2bf(v.y), h2 = f2bf(v.z), h3 = f2bf(v.w);
        *(ushort4*)&Xs[0][xr][xc] = make_ushort4(h0, h1, h2, h3);
        *(ushort4*)&Xs[1][xr][xc] = make_ushort4(
            f2bf(v.x - bf2f(h0)), f2bf(v.y - bf2f(h1)),
            f2bf(v.z - bf2f(h2)), f2bf(v.w - bf2f(h3)));
        #pragma unroll
        for (int j = 0; j < 3; ++j) {
            int idx = t + j * 256, n = idx >> 2, kc = (idx & 3) * 8;
            *(uint4*)&Ws[0][n][kc] = *(const uint4*)&WhT[n * DM + kb + k0 + kc];
            *(uint4*)&Ws[1][n][kc] = *(const uint4*)&WlT[n * DM + kb + k0 + kc];
        }
        __syncthreads();
        short8 ah[2], al[2];
        #pragma unroll
        for (int mi = 0; mi < 2; ++mi) {
            ah[mi] = *(const short8*)&Xs[0][mi * 16 + m_][qd * 8];
            al[mi] = *(const short8*)&Xs[1][mi * 16 + m_][qd * 8];
        }
        int nq = wave * 16 + m_, nk = 64 + wave * 16 + m_, nv = 128 + wave * 16 + m_;
        short8 bqh = *(const short8*)&Ws[0][nq][qd * 8];
        short8 bql = *(const short8*)&Ws[1][nq][qd * 8];
        short8 bkh = *(const short8*)&Ws[0][nk][qd * 8];
        short8 bkl = *(const short8*)&Ws[1][nk][qd * 8];
        short8 bvh = *(const short8*)&Ws[0][nv][qd * 8];
        #pragma unroll
        for (int mi = 0; mi < 2; ++mi) {
            accq[mi] = __builtin_amdgcn_mfma_f32_16x16x32_bf16(ah[mi], bqh, accq[mi], 0, 0, 0);
            accq[mi] = __builtin_amdgcn_mfma_f32_16x16x32_bf16(al[mi], bqh, accq[mi], 0, 0, 0);
            accq[mi] = __builtin_amdgcn_mfma_f32_16x16x32_bf16(ah[mi], bql, accq[mi], 0, 0, 0);
            acck[mi] = __builtin_amdgcn_mfma_f32_16x16x32_bf16(ah[mi], bkh, acck[mi], 0, 0, 0);
            acck[mi] = __builtin_amdgcn_mfma_f32_16x16x32_bf16(al[mi], bkh, acck[mi], 0, 0, 0);
            acck[mi] = __builtin_amdgcn_mfma_f32_16x16x32_bf16(ah[mi], bkl, acck[mi], 0, 0, 0);
            accv[mi] = __builtin_amdgcn_mfma_f32_16x16x32_bf16(ah[mi], bvh, accv[mi], 0, 0, 0);
        }
        __syncthreads();
    }
    float* Cp = Cpart + (size_t)blockIdx.y * (NROWS * 192);
    #pragma unroll
    for (int mi = 0; mi < 2; ++mi) {
        #pragma unroll
        for (int r = 0; r < 4; ++r) {
            int row = s0 + mi * 16 + qd * 4 + r;
            float* base = Cp + (size_t)row * 192;
            base[wave * 16 + m_]       = accq[mi][r];
            base[64 + wave * 16 + m_]  = acck[mi][r];
            base[128 + wave * 16 + m_] = accv[mi][r];
        }
    }
}

// ---------------- K1b: reduce partials, split hi/lo, permute xv ----------------
// 32 rows (= one 32-k chunk) per block. xvP layout [b][c32][qd][h][j]:
// element = xv[k = c32*32 + 16*(j>>2) + 4*qd + (j&3)][h]  (MFMA B-frag order).
__global__ __launch_bounds__(256) void qkv_reduce_kernel(
    const float* __restrict__ Cpart,
    ushort* __restrict__ qh, ushort* __restrict__ ql,
    ushort* __restrict__ kh, ushort* __restrict__ kl, ushort* __restrict__ xvP)
{
    __shared__ ushort xvs[32][72];
    const size_t SL = (size_t)NROWS * 192;
    int row0 = blockIdx.x * 32;
    int t = threadIdx.x;
    #pragma unroll
    for (int i = 0; i < 24; ++i) {
        int e = i * 256 + t;
        int r = e / 192, c = e - r * 192;
        size_t row = row0 + r;
        size_t off = row * 192 + c;
        float s = Cpart[off] + Cpart[SL + off] + Cpart[2 * SL + off] + Cpart[3 * SL + off];
        ushort hi = f2bf(s);
        if (c < 64) {
            qh[row * 64 + c] = hi; ql[row * 64 + c] = f2bf(s - bf2f(hi));
        } else if (c < 128) {
            kh[row * 64 + c - 64] = hi; kl[row * 64 + c - 64] = f2bf(s - bf2f(hi));
        } else {
            xvs[r][c - 128] = hi;
        }
    }
    __syncthreads();
    int h = t & 63, qd = t >> 6;          // 4 waves <-> qd 0..3
    ushortx8 v;
    #pragma unroll
    for (int j = 0; j < 8; ++j)
        v[j] = xvs[4 * qd + (j & 3) + ((j >> 2) << 4)][h];
    int b = row0 >> 11, c32 = (row0 & 2047) >> 5;
    *(ushortx8*)&xvP[((((size_t)b << 6) + c32) * 4 + qd) * 512 + h * 8] = v;
}

// ---------------- K2: fused attention ----------------
// Block = (pair pp, batch b): q-tiles jA=pp, jB=127-pp (16 rows each).
// 8 waves share the combined 64k-chunk list (nA+nB = 33/34, uniform).
// Per chunk: S^T = mfma(K,Q) hi/lo; lane holds S[k=qd*4+r(+16mt)][q=m_];
// mask+exp -> bf16 P A-frag in-register (k-order perm matches xvP); PV mfma.
// Epilogue: cross-wave O/l combine in LDS, scale 1/l, write Axv hi/lo.
__global__ __launch_bounds__(512) void attn_kernel(
    const ushort* __restrict__ qh, const ushort* __restrict__ ql,
    const ushort* __restrict__ kh, const ushort* __restrict__ kl,
    const ushort* __restrict__ xvP,
    ushort* __restrict__ Axvh, ushort* __restrict__ Axvl)
{
    __shared__ __align__(16) ushort Qs[2][2][16][72];  // [tile][hi/lo][row][col]
    __shared__ float LO[2][2][16][68];                 // [wavepart][tile][q][h]
    __shared__ float lred[8][2][16];                   // [wave][tile][q]
    int pp = blockIdx.x & 63, b = blockIdx.x >> 6;
    int srowA = pp << 4, srowB = (127 - pp) << 4;
    int t = threadIdx.x, wave = t >> 6, lane = t & 63, m_ = lane & 15, qd = lane >> 4;
    {   // stage Q tiles: 512 threads x 1 uint4
        int tile = t >> 8, hl = (t >> 7) & 1, r = (t >> 3) & 15, c = (t & 7) * 8;
        const ushort* src = (hl ? ql : qh) + (size_t)((b << 11) + (tile ? srowB : srowA) + r) * 64 + c;
        *(uint4*)&Qs[tile][hl][r][c] = *(const uint4*)src;
    }
    __syncthreads();
    int nA = (pp >> 2) + 1, nB = ((127 - pp) >> 2) + 1;
    int M = nA + nB;
    const ushort* khb = kh + (((size_t)b << 11)) * 64;
    const ushort* klb = kl + (((size_t)b << 11)) * 64;
    const ushort* xvb = xvP + ((size_t)b << 17);       // 64*4*64*8 per batch
    const floatx4 z4 = {0.f, 0.f, 0.f, 0.f};
    floatx4 accOA[4] = {z4, z4, z4, z4};
    floatx4 accOB[4] = {z4, z4, z4, z4};
    float llA = 0.f, llB = 0.f;
    for (int it = wave; it < M; it += 8) {
        int tile = (it >= nA);
        int c = tile ? (it - nA) : it;
        int srow = tile ? srowB : srowA;
        int k0 = c << 6;
        floatx4 accS[4] = {z4, z4, z4, z4};
        #pragma unroll
        for (int kk = 0; kk < 2; ++kk) {
            short8 bqh, bql;
            if (tile == 0) {
                bqh = *(const short8*)&Qs[0][0][m_][kk * 32 + qd * 8];
                bql = *(const short8*)&Qs[0][1][m_][kk * 32 + qd * 8];
            } else {
                bqh = *(const short8*)&Qs[1][0][m_][kk * 32 + qd * 8];
                bql = *(const short8*)&Qs[1][1][m_][kk * 32 + qd * 8];
            }
            #pragma unroll
            for (int mt = 0; mt < 4; ++mt) {
                size_t koff = (size_t)(k0 + mt * 16 + m_) * 64 + kk * 32 + qd * 8;
                short8 akh = *(const short8*)&khb[koff];
                short8 akl = *(const short8*)&klb[koff];
                accS[mt] = __builtin_amdgcn_mfma_f32_16x16x32_bf16(akh, bqh, accS[mt], 0, 0, 0);
                accS[mt] = __builtin_amdgcn_mfma_f32_16x16x32_bf16(akl, bqh, accS[mt], 0, 0, 0);
                accS[mt] = __builtin_amdgcn_mfma_f32_16x16x32_bf16(akh, bql, accS[mt], 0, 0, 0);
            }
        }
        int qrow = srow + m_;
        float lsum = 0.f;
        short8 pa[2];
        #pragma unroll
        for (int h2 = 0; h2 < 2; ++h2) {
            #pragma unroll
            for (int tt = 0; tt < 2; ++tt) {
                int mt = h2 * 2 + tt;
                #pragma unroll
                for (int r = 0; r < 4; ++r) {
                    int kc = k0 + mt * 16 + qd * 4 + r;
                    float p = (kc <= qrow) ? __expf(accS[mt][r]) : 0.f;
                    lsum += p;
                    pa[h2][tt * 4 + r] = (short)f2bf(p);
                }
            }
        }
        if (tile == 0) llA += lsum; else llB += lsum;
        #pragma unroll
        for (int h2 = 0; h2 < 2; ++h2) {
            int c32 = (k0 >> 5) + h2;
            const ushort* xb = xvb + ((size_t)c32 * 4 + qd) * 512 + m_ * 8;
            short8 x0 = *(const short8*)&xb[0];
            short8 x1 = *(const short8*)&xb[128];
            short8 x2 = *(const short8*)&xb[256];
            short8 x3 = *(const short8*)&xb[384];
            if (tile == 0) {
                accOA[0] = __builtin_amdgcn_mfma_f32_16x16x32_bf16(pa[h2], x0, accOA[0], 0, 0, 0);
                accOA[1] = __builtin_amdgcn_mfma_f32_16x16x32_bf16(pa[h2], x1, accOA[1], 0, 0, 0);
                accOA[2] = __builtin_amdgcn_mfma_f32_16x16x32_bf16(pa[h2], x2, accOA[2], 0, 0, 0);
                accOA[3] = __builtin_amdgcn_mfma_f32_16x16x32_bf16(pa[h2], x3, accOA[3], 0, 0, 0);
            } else {
                accOB[0] = __builtin_amdgcn_mfma_f32_16x16x32_bf16(pa[h2], x0, accOB[0], 0, 0, 0);
                accOB[1] = __builtin_amdgcn_mfma_f32_16x16x32_bf16(pa[h2], x1, accOB[1], 0, 0, 0);
                accOB[2] = __builtin_amdgcn_mfma_f32_16x16x32_bf16(pa[h2], x2, accOB[2], 0, 0, 0);
                accOB[3] = __builtin_amdgcn_mfma_f32_16x16x32_bf16(pa[h2], x3, accOB[3], 0, 0, 0);
            }
        }
    }
    // l: reduce over qd lanes -> full partial for q=m_
    llA += __shfl_xor(llA, 16); llA += __shfl_xor(llA, 32);
    llB += __shfl_xor(llB, 16); llB += __shfl_xor(llB, 32);
    if (qd == 0) { lred[wave][0][m_] = llA; lred[wave][1][m_] = llB; }
    // O: cross-wave combine (waves 0-3 -> part 0, waves 4-7 -> part 1)
    int part = wave >> 2, w4 = wave & 3;
    for (int w = 0; w < 4; ++w) {
        if (w4 == w) {
            #pragma unroll
            for (int hn = 0; hn < 4; ++hn)
                #pragma unroll
                for (int r = 0; r < 4; ++r) {
                    int q = qd * 4 + r, h = hn * 16 + m_;
                    if (w == 0) {
                        LO[part][0][q][h] = accOA[hn][r];
                        LO[part][1][q][h] = accOB[hn][r];
                    } else {
                        LO[part][0][q][h] += accOA[hn][r];
                        LO[part][1][q][h] += accOB[hn][r];
                    }
                }
        }
        __syncthreads();
    }
    // write: 2048 elems / 512 threads = 4 each
    int tile2 = t >> 8, qq = (t >> 4) & 15, h0 = (t & 15) * 4;
    int srow2 = tile2 ? srowB : srowA;
    float lt = 0.f;
    #pragma unroll
    for (int w = 0; w < 8; ++w) lt += lred[w][tile2][qq];
    float sc = 1.f / lt;
    ushort4 hv, lv;
    float v0 = (LO[0][tile2][qq][h0 + 0] + LO[1][tile2][qq][h0 + 0]) * sc;
    float v1 = (LO[0][tile2][qq][h0 + 1] + LO[1][tile2][qq][h0 + 1]) * sc;
    float v2 = (LO[0][tile2][qq][h0 + 2] + LO[1][tile2][qq][h0 + 2]) * sc;
    float v3 = (LO[0][tile2][qq][h0 + 3] + LO[1][tile2][qq][h0 + 3]) * sc;
    hv.x = f2bf(v0); lv.x = f2bf(v0 - bf2f(hv.x));
    hv.y = f2bf(v1); lv.y = f2bf(v1 - bf2f(hv.y));
    hv.z = f2bf(v2); lv.z = f2bf(v2 - bf2f(hv.z));
    hv.w = f2bf(v3); lv.w = f2bf(v3 - bf2f(hv.w));
    size_t orow = (size_t)((b << 11) + srow2 + qq) * 64 + h0;
    *(ushort4*)&Axvh[orow] = hv;
    *(ushort4*)&Axvl[orow] = lv;
}

// ---------------- K3: out = Axv @ O^T (bf16 hi/lo GEMM, write-bound) ----------------
__global__ __launch_bounds__(256) void out_kernel(
    const ushort* __restrict__ Axvh, const ushort* __restrict__ Axvl,
    const ushort* __restrict__ Oh, const ushort* __restrict__ Ol,
    float* __restrict__ out)
{
    __shared__ __align__(16) ushort As[2][64][72];
    __shared__ __align__(16) ushort Bsh[2][128][72];
    int bid = blockIdx.x;
    int r0 = (bid >> 3) << 6;        // global row 0..8128
    int e0 = (bid & 7) << 7;         // 0..896
    int t = threadIdx.x;
    {   // A: 64 rows x 64 cols x 2 planes
        int tr = t >> 2, tc = (t & 3) << 4;
        const ushort* ah = Axvh + (size_t)(r0 + tr) * DH + tc;
        const ushort* al = Axvl + (size_t)(r0 + tr) * DH + tc;
        *(uint4*)&As[0][tr][tc]     = *(const uint4*)ah;
        *(uint4*)&As[0][tr][tc + 8] = *(const uint4*)(ah + 8);
        *(uint4*)&As[1][tr][tc]     = *(const uint4*)al;
        *(uint4*)&As[1][tr][tc + 8] = *(const uint4*)(al + 8);
    }
    {   // B: 128 rows x 64 cols x 2 planes
        int tr = t >> 1, tc = (t & 1) << 5;
        const ushort* bh = Oh + (size_t)(e0 + tr) * DH + tc;
        const ushort* bl = Ol + (size_t)(e0 + tr) * DH + tc;
        *(uint4*)&Bsh[0][tr][tc]      = *(const uint4*)bh;
        *(uint4*)&Bsh[0][tr][tc + 8]  = *(const uint4*)(bh + 8);
        *(uint4*)&Bsh[0][tr][tc + 16] = *(const uint4*)(bh + 16);
        *(uint4*)&Bsh[0][tr][tc + 24] = *(const uint4*)(bh + 24);
        *(uint4*)&Bsh[1][tr][tc]      = *(const uint4*)bl;
        *(uint4*)&Bsh[1][tr][tc + 8]  = *(const uint4*)(bl + 8);
        *(uint4*)&Bsh[1][tr][tc + 16] = *(const uint4*)(bl + 16);
        *(uint4*)&Bsh[1][tr][tc + 24] = *(const uint4*)(bl + 24);
    }
    __syncthreads();
    int wave = t >> 6, lane = t & 63, m_ = lane & 15, qd = lane >> 4;
    const floatx4 z4 = {0.f, 0.f, 0.f, 0.f};
    floatx4 acc[8] = {z4, z4, z4, z4, z4, z4, z4, z4};
    #pragma unroll
    for (int kk = 0; kk < 2; ++kk) {
        short8 ah = *(const short8*)&As[0][wave * 16 + m_][kk * 32 + qd * 8];
        short8 al = *(const short8*)&As[1][wave * 16 + m_][kk * 32 + qd * 8];
        #pragma unroll
        for (int ni = 0; ni < 8; ++ni) {
            short8 bh = *(const short8*)&Bsh[0][ni * 16 + m_][kk * 32 + qd * 8];
            short8 bl = *(const short8*)&Bsh[1][ni * 16 + m_][kk * 32 + qd * 8];
            acc[ni] = __builtin_amdgcn_mfma_f32_16x16x32_bf16(ah, bh, acc[ni], 0, 0, 0);
            acc[ni] = __builtin_amdgcn_mfma_f32_16x16x32_bf16(al, bh, acc[ni], 0, 0, 0);
            acc[ni] = __builtin_amdgcn_mfma_f32_16x16x32_bf16(ah, bl, acc[ni], 0, 0, 0);
        }
    }
    #pragma unroll
    for (int r = 0; r < 4; ++r) {
        int row = r0 + wave * 16 + qd * 4 + r;
        float* orow = out + (size_t)row * DM + e0;
        #pragma unroll
        for (int ni = 0; ni < 8; ++ni)
            orow[ni * 16 + m_] = acc[ni][r];
    }
}

extern "C" void kernel_launch(void* const* d_in, const int* in_sizes, int n_in,
                              void* d_out, int out_size, void* d_ws, size_t ws_size,
                              hipStream_t stream) {
    const float* x = (const float*)d_in[0];
    const float* Q = (const float*)d_in[1];
    const float* K = (const float*)d_in[2];
    const float* V = (const float*)d_in[3];
    const float* O = (const float*)d_in[4];
    float* out = (float*)d_out;

    char* ws = (char*)d_ws;
    ushort* qh   = (ushort*)(ws);                    // 1 MB [8192][64] bf16
    ushort* ql   = (ushort*)(ws + (1ull  << 20));
    ushort* kh   = (ushort*)(ws + (2ull  << 20));
    ushort* kl   = (ushort*)(ws + (3ull  << 20));
    ushort* xvP  = (ushort*)(ws + (4ull  << 20));    // 1 MB [4][64][4][64][8] permuted xv
    ushort* WhT  = (ushort*)(ws + (5ull  << 20));    // 384 KB [192][1024]
    ushort* WlT  = (ushort*)(ws + (5ull  << 20) + (512ull << 10));
    ushort* Oh   = (ushort*)(ws + (6ull  << 20));                   // 128 KB [1024][64]
    ushort* Ol   = (ushort*)(ws + (6ull  << 20) + (128ull << 10));  // 128 KB
    ushort* Axvh = (ushort*)(ws + (7ull  << 20));    // 1 MB [8192][64] bf16
    ushort* Axvl = (ushort*)(ws + (8ull  << 20));    // 1 MB
    float*  Cpart = (float*)(ws + (23ull << 20));    // 25 MB [4][8192][192]

    wprep_kernel<<<256, 256, 0, stream>>>(Q, K, V, O, WhT, WlT, Oh, Ol);
    qkv_part_kernel<<<dim3(NROWS / 32, 4), 256, 0, stream>>>(x, WhT, WlT, Cpart);
    qkv_reduce_kernel<<<NROWS / 32, 256, 0, stream>>>(Cpart, qh, ql, kh, kl, xvP);
    attn_kernel<<<64 * BATCH, 512, 0, stream>>>(qh, ql, kh, kl, xvP, Axvh, Axvl);
    out_kernel<<<(NROWS / 64) * 8, 256, 0, stream>>>(Axvh, Axvl, Oh, Ol, out);
}